// Round 2
// baseline (648.502 us; speedup 1.0000x reference)
//
#include <hip/hip_runtime.h>
#include <hip/hip_bf16.h>
#include <stdint.h>

// B=16, S=2048, D=64. All fp32 I/O; mask int32 (nonzero == masked -> -1e30).
// d_in: q[B,S,D] f32, k[B,S,D] f32, v[B,S,D] f32, mask[B,S,S] i32
// d_out: output[B,S,D] f32 (2097152 floats) then attn[B,S,S] f32.
//
// One block = one 16-row q-tile of one batch. 8 waves/block; wave w owns
// keys [w*256, w*256+256). Scores kept in MFMA C-frags (64 VGPR/lane).
// QK^T: 3-term bf16 split MFMA (q_hi*k_hi + q_hi*k_lo + q_lo*k_hi) -> ~fp32
// accuracy. PV: plain bf16 MFMA. P goes C-layout -> A-layout via LDS.

#define S_DIM 2048
#define D_DIM 64

typedef short short8 __attribute__((ext_vector_type(8)));
typedef float floatx4 __attribute__((ext_vector_type(4)));

__device__ __forceinline__ unsigned short f2bf(float x) {
    uint32_t u = __float_as_uint(x);
    u += 0x7fffu + ((u >> 16) & 1u);
    return (unsigned short)(u >> 16);
}

__global__ __launch_bounds__(512) void attn_fused(
    const float* __restrict__ q, const float* __restrict__ k,
    const float* __restrict__ v, const int* __restrict__ mask,
    float* __restrict__ out, float* __restrict__ attn)
{
    __shared__ __align__(16) float qlds[16 * 68];            // 4.4 KB
    __shared__ __align__(16) unsigned short pbuf[8 * 16 * 36]; // 9.2 KB (per-wave 16x32+pad)
    __shared__ __align__(16) float obuf[8 * 16 * 68];        // 34.8 KB
    __shared__ float mxtab[8 * 16];
    __shared__ float ltab[8 * 16];

    const int tid  = threadIdx.x;
    const int w    = tid >> 6;
    const int lane = tid & 63;
    const int quad = lane >> 4;
    const int n16  = lane & 15;
    const int b    = blockIdx.x >> 7;     // 128 q-tiles per batch
    const int q0   = (blockIdx.x & 127) * 16;
    const int key0 = w * 256;

    // ---------------- Phase A: Q tile -> LDS, build A-frags (hi/lo) -------
    {
        int m = tid >> 5, d = (tid & 31) * 2;
        float2 qv = *(const float2*)(q + ((size_t)(b * S_DIM + q0 + m)) * D_DIM + d);
        qlds[m * 68 + d]     = qv.x;
        qlds[m * 68 + d + 1] = qv.y;
    }
    __syncthreads();

    short8 ahi[2], alo[2];
    #pragma unroll
    for (int s = 0; s < 2; ++s) {
        const float* qp = &qlds[n16 * 68 + s * 32 + quad * 8];
        union { __hip_bfloat162 h[4]; short8 v; } H, L;
        #pragma unroll
        for (int p = 0; p < 4; ++p) {
            float x0 = qp[2 * p], x1 = qp[2 * p + 1];
            __hip_bfloat162 h2 = __float22bfloat162_rn(float2{x0, x1});
            float l0 = x0 - __bfloat162float(h2.x);
            float l1 = x1 - __bfloat162float(h2.y);
            H.h[p] = h2;
            L.h[p] = __float22bfloat162_rn(float2{l0, l1});
        }
        ahi[s] = H.v; alo[s] = L.v;
    }

    // ---------------- Phase B: scores = QK^T/8, masked --------------------
    // C-frag c: key = key0 + c*16 + n16 (col), q-row = q0 + quad*4 + reg.
    floatx4 sc[16];
    const size_t kvbase = (size_t)(b * S_DIM) * D_DIM;
    #pragma unroll
    for (int c = 0; c < 16; ++c) {
        const int key = key0 + c * 16 + n16;
        const int* mp = mask + (size_t)(b * S_DIM + q0 + quad * 4) * S_DIM + key;
        int mk0 = mp[0], mk1 = mp[S_DIM], mk2 = mp[2 * S_DIM], mk3 = mp[3 * S_DIM];
        floatx4 acc = {0.f, 0.f, 0.f, 0.f};
        #pragma unroll
        for (int s = 0; s < 2; ++s) {
            const float* kp = k + kvbase + (size_t)key * D_DIM + s * 32 + quad * 8;
            float4 k0 = *(const float4*)kp;
            float4 k1 = *(const float4*)(kp + 4);
            float kf[8] = {k0.x, k0.y, k0.z, k0.w, k1.x, k1.y, k1.z, k1.w};
            union { __hip_bfloat162 h[4]; short8 v; } BH, BL;
            #pragma unroll
            for (int p = 0; p < 4; ++p) {
                float x0 = kf[2 * p], x1 = kf[2 * p + 1];
                __hip_bfloat162 h2 = __float22bfloat162_rn(float2{x0, x1});
                BH.h[p] = h2;
                BL.h[p] = __float22bfloat162_rn(
                    float2{x0 - __bfloat162float(h2.x), x1 - __bfloat162float(h2.y)});
            }
            acc = __builtin_amdgcn_mfma_f32_16x16x32_bf16(ahi[s], BH.v, acc, 0, 0, 0);
            acc = __builtin_amdgcn_mfma_f32_16x16x32_bf16(ahi[s], BL.v, acc, 0, 0, 0);
            acc = __builtin_amdgcn_mfma_f32_16x16x32_bf16(alo[s], BH.v, acc, 0, 0, 0);
        }
        sc[c][0] = mk0 ? -1e30f : acc[0] * 0.125f;
        sc[c][1] = mk1 ? -1e30f : acc[1] * 0.125f;
        sc[c][2] = mk2 ? -1e30f : acc[2] * 0.125f;
        sc[c][3] = mk3 ? -1e30f : acc[3] * 0.125f;
    }

    // ---------------- Phase C: exact softmax over 2048 keys ---------------
    #pragma unroll
    for (int r = 0; r < 4; ++r) {
        float mx = sc[0][r];
        #pragma unroll
        for (int c = 1; c < 16; ++c) mx = fmaxf(mx, sc[c][r]);
        #pragma unroll
        for (int o = 1; o < 16; o <<= 1) mx = fmaxf(mx, __shfl_xor(mx, o, 64));
        if (n16 == 0) mxtab[w * 16 + quad * 4 + r] = mx;
    }
    __syncthreads();
    #pragma unroll
    for (int r = 0; r < 4; ++r) {
        float mf = -3e38f;
        #pragma unroll
        for (int w2 = 0; w2 < 8; ++w2) mf = fmaxf(mf, mxtab[w2 * 16 + quad * 4 + r]);
        float l = 0.f;
        #pragma unroll
        for (int c = 0; c < 16; ++c) {
            float e = __expf(sc[c][r] - mf);
            sc[c][r] = e;
            l += e;
        }
        #pragma unroll
        for (int o = 1; o < 16; o <<= 1) l += __shfl_xor(l, o, 64);
        if (n16 == 0) ltab[w * 16 + quad * 4 + r] = l;
    }
    __syncthreads();
    #pragma unroll
    for (int r = 0; r < 4; ++r) {
        float l = 0.f;
        #pragma unroll
        for (int w2 = 0; w2 < 8; ++w2) l += ltab[w2 * 16 + quad * 4 + r];
        float inv = 1.0f / l;
        #pragma unroll
        for (int c = 0; c < 16; ++c) sc[c][r] *= inv;
    }

    // ---------------- Phase D: write attn (fp32, 64B-coalesced/quad) ------
    {
        float* arow = attn + (size_t)(b * S_DIM + q0 + quad * 4) * S_DIM + key0 + n16;
        #pragma unroll
        for (int c = 0; c < 16; ++c) {
            #pragma unroll
            for (int r = 0; r < 4; ++r) arow[(size_t)r * S_DIM + c * 16] = sc[c][r];
        }
    }

    // ---------------- Phase E: O += P*V (bf16 MFMA), P via LDS transpose --
    floatx4 o0 = {0,0,0,0}, o1 = {0,0,0,0}, o2 = {0,0,0,0}, o3 = {0,0,0,0};
    unsigned short* pw = pbuf + w * 576;   // 16 rows x 36 (32 keys + pad)
    #pragma unroll
    for (int s2 = 0; s2 < 8; ++s2) {
        #pragma unroll
        for (int h = 0; h < 2; ++h) {
            const int c = s2 * 2 + h;
            #pragma unroll
            for (int r = 0; r < 4; ++r)
                pw[(quad * 4 + r) * 36 + h * 16 + n16] = f2bf(sc[c][r]);
        }
        __syncthreads();
        short8 pa;
        {
            const uint32_t* pr = (const uint32_t*)((const char*)pbuf +
                                   (size_t)w * 1152 + n16 * 72 + quad * 16);
            union { uint32_t u[4]; short8 v; } P;
            P.u[0] = pr[0]; P.u[1] = pr[1]; P.u[2] = pr[2]; P.u[3] = pr[3];
            pa = P.v;
        }
        const size_t vrow0 = (size_t)(b * S_DIM + key0 + s2 * 32 + quad * 8) * D_DIM;
        #pragma unroll
        for (int nc = 0; nc < 4; ++nc) {
            const float* vp = v + vrow0 + nc * 16 + n16;
            union { __hip_bfloat162 h[4]; short8 v8; } BV;
            #pragma unroll
            for (int p = 0; p < 4; ++p) {
                float x0 = vp[(size_t)(2 * p) * D_DIM];
                float x1 = vp[(size_t)(2 * p + 1) * D_DIM];
                BV.h[p] = __float22bfloat162_rn(float2{x0, x1});
            }
            floatx4& oo = (nc == 0 ? o0 : nc == 1 ? o1 : nc == 2 ? o2 : o3);
            oo = __builtin_amdgcn_mfma_f32_16x16x32_bf16(pa, BV.v8, oo, 0, 0, 0);
        }
        __syncthreads();
    }

    // ---------------- Phase F: reduce per-wave partial O, store -----------
    #pragma unroll
    for (int nc = 0; nc < 4; ++nc) {
        floatx4 oo = (nc == 0 ? o0 : nc == 1 ? o1 : nc == 2 ? o2 : o3);
        #pragma unroll
        for (int i = 0; i < 4; ++i)
            obuf[(w * 16 + quad * 4 + i) * 68 + nc * 16 + n16] = oo[i];
    }
    __syncthreads();
    #pragma unroll
    for (int t2 = 0; t2 < 2; ++t2) {
        int idx = tid + t2 * 512;
        int m = idx >> 6, d = idx & 63;
        float a = 0.f;
        #pragma unroll
        for (int w2 = 0; w2 < 8; ++w2) a += obuf[(w2 * 16 + m) * 68 + d];
        out[(size_t)(b * S_DIM + q0 + m) * D_DIM + d] = a;
    }
}

extern "C" void kernel_launch(void* const* d_in, const int* in_sizes, int n_in,
                              void* d_out, int out_size, void* d_ws, size_t ws_size,
                              hipStream_t stream) {
    const float* q    = (const float*)d_in[0];
    const float* k    = (const float*)d_in[1];
    const float* v    = (const float*)d_in[2];
    const int*   mask = (const int*)d_in[3];

    float* out  = (float*)d_out;
    float* attn = out + (size_t)16 * S_DIM * D_DIM;   // 2,097,152 floats

    attn_fused<<<dim3(2048), dim3(512), 0, stream>>>(q, k, v, mask, out, attn);
}